// Round 14
// baseline (94.344 us; speedup 1.0000x reference)
//
#include <hip/hip_runtime.h>
#include <hip/hip_bf16.h>

// Problem constants
#define Dm   1024
#define Hh   16
#define HDq  64
#define DKV  512
#define HID  128
#define Bb   2
#define Ll   2048
#define Ff   32

typedef _Float16 half8 __attribute__((ext_vector_type(8)));
typedef _Float16 half4v __attribute__((ext_vector_type(4)));
typedef float f32x4 __attribute__((ext_vector_type(4)));

__device__ __forceinline__ float gelu_exact(float x) {
    return 0.5f * x * (1.0f + erff(x * 0.70710678118654752f));
}

// ---------------------------------------------------------------------------
// kprep2: grid (32 jt, Bb) = 64 blocks. Each block REDUNDANTLY computes the
// whole w_comb[b] chain from scratch (no partials, no prior kernel):
//   hid (tau+delta, 1024-deep coalesced row-loop) -> gelu -> tau / gh
//   Qc (needed Wq half-cols only, row-loop) ; delta2 = gh @ dw2
//   wc[c] = tau*Qc/sqrt(32)+clip(delta) ; then its 32-row Wk slice -> kwh16.
// ---------------------------------------------------------------------------
__global__ __launch_bounds__(256) void kprep2(
        const float* __restrict__ h,
        const float* __restrict__ mu, const float* __restrict__ sigma,
        const float* __restrict__ Wq, const float* __restrict__ Wk,
        const float* __restrict__ tw1, const float* __restrict__ tb1,
        const float* __restrict__ tw2, const float* __restrict__ tb2,
        const float* __restrict__ dw1, const float* __restrict__ db1,
        const float* __restrict__ dw2, const float* __restrict__ db2,
        _Float16* __restrict__ kwh16)
{
    const int jt = blockIdx.x, b = blockIdx.y;
    const int t = threadIdx.x;
    __shared__ float hl[Dm];
    __shared__ float red[256];
    __shared__ float redB[256];
    __shared__ f32x4 qpart[128];
    __shared__ float gh[HID];
    __shared__ float qc[DKV];
    __shared__ float wc[DKV];
    __shared__ float kl[16][36];
    __shared__ float s_tau, s_sm, s_mm;

    // h_last -> LDS
    {
        float4 v = *(const float4*)(h + ((size_t)b * Ll + (Ll - 1)) * Dm + t * 4);
        *(float4*)(hl + t * 4) = v;
    }
    if (t == 0) {
        float s = 0.f;
        for (int f = 0; f < Ff; ++f) s += sigma[((size_t)b * Ll + (Ll - 1)) * Ff + f];
        s_sm = fmaxf(s / (float)Ff, 1e-6f);
    }
    if (t == 64) {
        float s = 0.f;
        for (int f = 0; f < Ff; ++f) s += mu[((size_t)b * Ll + (Ll - 1)) * Ff + f];
        s_mm = s / (float)Ff;
    }
    __syncthreads();

    // hid: col = t&127, row-half rg = t>>7 (512 rows each), both MLPs fused
    const int col = t & 127, rg = t >> 7;
    {
        float at = 0.f, ad = 0.f;
        const int j0 = rg * 512;
#pragma unroll 8
        for (int i = 0; i < 512; ++i) {
            const float x = hl[j0 + i];
            at += x * tw1[(size_t)(j0 + i + 1) * HID + col];
            ad += x * dw1[(size_t)(j0 + i + 1) * HID + col];
        }
        red[t] = at; redB[t] = ad;
    }
    __syncthreads();
    float tauterm = 0.f;
    if (t < 128) {
        float a  = red[t] + red[t + 128] + tb1[t] + s_sm * tw1[t];
        float ad = redB[t] + redB[t + 128] + db1[t] + s_mm * dw1[t];
        gh[t] = gelu_exact(ad);
        tauterm = gelu_exact(a) * tw2[t];
    }
    __syncthreads();
    red[t] = (t < 128) ? tauterm : 0.f;
    __syncthreads();
    for (int s = 128; s > 0; s >>= 1) {
        if (t < s) red[t] += red[t + s];
        __syncthreads();
    }
    if (t == 0) {
        float s = red[0] + tb2[0];
        s_tau = expf(fminf(fmaxf(s, -3.f), 3.f));
    }

    // Qc: quad q = t&127 covers c = 4q (head = q>>3, d = (q&7)*4); row-half rh
    {
        const int q = t & 127, rh = t >> 7;
        const int colq = (q >> 3) * HDq + (q & 7) * 4;
        f32x4 aq = {};
        const int j0 = rh * 512;
#pragma unroll 8
        for (int i = 0; i < 512; ++i) {
            const float x = hl[j0 + i];
            f32x4 wq = *(const f32x4*)(Wq + (size_t)(j0 + i) * Dm + colq);
            aq += x * wq;
        }
        if (rh == 1) qpart[q] = aq;
        __syncthreads();
        if (rh == 0) {
            f32x4 s = aq + qpart[q];
            *(f32x4*)(qc + q * 4) = s;
        }
    }
    __syncthreads();

    // delta2 + combine -> wc
    {
        const int c0 = t, c1 = t + 256;
        float d0 = db2[c0], d1 = db2[c1];
#pragma unroll 16
        for (int i = 0; i < HID; ++i) {
            const float x = gh[i];
            d0 += x * dw2[(size_t)i * DKV + c0];
            d1 += x * dw2[(size_t)i * DKV + c1];
        }
        d0 = fminf(fmaxf(d0, -5.f), 5.f);
        d1 = fminf(fmaxf(d1, -5.f), 5.f);
        const float inv_sqrt = 0.17677669529663687f;
        wc[c0] = s_tau * qc[c0] * inv_sqrt + d0;
        wc[c1] = s_tau * qc[c1] * inv_sqrt + d1;
    }
    __syncthreads();

    // Wk slice: 32 j rows -> one fp16 chunk (proven R8/R13 code)
    const float w0 = wc[t * 2], w1v = wc[t * 2 + 1];
    const int hd = t >> 4;
#pragma unroll 4
    for (int jj = 0; jj < 32; ++jj) {
        const int j = jt * 32 + jj;
        float2 kv = *(const float2*)(Wk + (size_t)j * DKV + t * 2);
        float p = kv.x * w0 + kv.y * w1v;
        p += __shfl_xor(p, 1); p += __shfl_xor(p, 2);
        p += __shfl_xor(p, 4); p += __shfl_xor(p, 8);
        if ((t & 15) == 0) kl[hd][jj] = p;
    }
    __syncthreads();
    if (t < 64) {
        const int head = t & 15, jl = (t >> 4) * 8;
        half8 v;
#pragma unroll
        for (int e = 0; e < 8; ++e) v[e] = (_Float16)kl[head][jl + e];
        *(half8*)(kwh16 + ((size_t)(b * 32 + jt)) * 512 + t * 8) = v;
    }
}

// ---------------------------------------------------------------------------
// kmid: grid (128 rt, Bb) = 256 blocks, 16-row tiles; h read ONCE.
//  phase 1: logits via MFMA (4-wave k-split) -> per-(tile,head) max m ->
//           p = exp(val - m) in (0,1] -> m_part, den_part
//  phase 2: hbar16[(b*128+rt)][h][j] = sum_{l<16} p[l][h]*h[row0+l][j]  (fp16)
// ---------------------------------------------------------------------------
__global__ __launch_bounds__(256) void kmid(
        const float* __restrict__ h, const _Float16* __restrict__ kwh16,
        float* __restrict__ m_part, float* __restrict__ den_part,
        _Float16* __restrict__ hbar16)
{
    __shared__ __align__(16) _Float16 Kw[16384];      // 32 KB
    __shared__ float lred[4][16][17];
    __shared__ float p_lds[16][16];
    __shared__ float m_s[16];
    const int rt = blockIdx.x, b = blockIdx.y;
    const int t = threadIdx.x;
    const int w = t >> 6, l = t & 63;
    const int rows0 = (b * 128 + rt) * 16;

#pragma unroll
    for (int i = 0; i < 8; ++i) {
        const int idx = i * 256 + t;
        *(half8*)(Kw + idx * 8) = *(const half8*)(kwh16 + (size_t)b * 16384 + idx * 8);
    }
    __syncthreads();

    // phase 1: one 16-row m-tile, 4-wave k-split (8 k-steps each)
    f32x4 lacc = {};
    const float* ap = h + (size_t)(rows0 + (l & 15)) * Dm + (l >> 4) * 8;
#pragma unroll
    for (int ks = 0; ks < 8; ++ks) {
        const int kt = w * 8 + ks;
        float4 x0 = *(const float4*)(ap + kt * 32);
        float4 x1 = *(const float4*)(ap + kt * 32 + 4);
        half8 af;
        af[0] = (_Float16)x0.x; af[1] = (_Float16)x0.y; af[2] = (_Float16)x0.z; af[3] = (_Float16)x0.w;
        af[4] = (_Float16)x1.x; af[5] = (_Float16)x1.y; af[6] = (_Float16)x1.z; af[7] = (_Float16)x1.w;
        half8 kf = *(const half8*)(Kw + kt * 512 + l * 8);
        lacc = __builtin_amdgcn_mfma_f32_16x16x32_f16(af, kf, lacc, 0, 0, 0);
    }
#pragma unroll
    for (int r = 0; r < 4; ++r)
        lred[w][(l >> 4) * 4 + r][l & 15] = lacc[r];
    __syncthreads();

    {
        const int row = t >> 4, head = t & 15;        // 256 = 16 x 16
        float val = lred[0][row][head] + lred[1][row][head]
                  + lred[2][row][head] + lred[3][row][head];
        val = fminf(fmaxf(val, -50.f), 50.f);
        p_lds[row][head] = val;
    }
    __syncthreads();
    if (t < 16) {
        float m = -1e30f;
#pragma unroll
        for (int r = 0; r < 16; ++r) m = fmaxf(m, p_lds[r][t]);
        m_s[t] = m;
        m_part[((size_t)b * Hh + t) * 128 + rt] = m;
    }
    __syncthreads();
    {
        const int row = t >> 4, head = t & 15;
        p_lds[row][head] = __expf(p_lds[row][head] - m_s[head]);
    }
    __syncthreads();
    if (t < 16) {
        float s = 0.f;
#pragma unroll
        for (int r = 0; r < 16; ++r) s += p_lds[r][t];
        den_part[((size_t)b * Hh + t) * 128 + rt] = s;
    }

    // phase 2: thread covers 16 j x 4 heads; h rows L2-hot from phase 1
    const int j0 = (t & 63) * 16;
    const int h0 = (t >> 6) * 4;                      // wave-uniform
    f32x4 acc2[4][4] = {};                            // [jj][hh]
#pragma unroll 4
    for (int l2 = 0; l2 < 16; ++l2) {
        const float* hr = h + (size_t)(rows0 + l2) * Dm + j0;
        f32x4 hv[4];
#pragma unroll
        for (int jj = 0; jj < 4; ++jj) hv[jj] = *(const f32x4*)(hr + jj * 4);
        f32x4 pp = *(const f32x4*)(&p_lds[l2][h0]);
#pragma unroll
        for (int hh = 0; hh < 4; ++hh)
#pragma unroll
            for (int jj = 0; jj < 4; ++jj)
                acc2[jj][hh] += hv[jj] * pp[hh];
    }
#pragma unroll
    for (int hh = 0; hh < 4; ++hh) {
        _Float16* dst = hbar16 + ((size_t)(b * 128 + rt) * Hh + h0 + hh) * Dm + j0;
        half8 v0, v1;
#pragma unroll
        for (int e = 0; e < 4; ++e) {
            v0[e]     = (_Float16)acc2[0][hh][e];
            v0[e + 4] = (_Float16)acc2[1][hh][e];
            v1[e]     = (_Float16)acc2[2][hh][e];
            v1[e + 4] = (_Float16)acc2[3][hh][e];
        }
        *(half8*)dst = v0;
        *(half8*)(dst + 8) = v1;
    }
}

// ---------------------------------------------------------------------------
// kopre: grid (16 h, Bb, 8 js). Weighted (e^{m_t-M}) reduce of 128 fp16
// tile-parts over its 128-j slice, then Wv matvec partial -> opre_part.
// ---------------------------------------------------------------------------
__global__ __launch_bounds__(256) void kopre(
        const _Float16* __restrict__ hbar16, const float* __restrict__ m_part,
        const float* __restrict__ Wv, float* __restrict__ opre_part)
{
    const int hd = blockIdx.x, b = blockIdx.y, js = blockIdx.z;
    const int t = threadIdx.x;
    __shared__ f32x4 pA[32][8];
    __shared__ float hb[128];
    __shared__ float red[256];
    __shared__ float w_s[128];
    __shared__ float Msh;

    // per-(b,h) tile max M and weights
    float mt = -1e30f;
    if (t < 128) mt = m_part[((size_t)b * Hh + hd) * 128 + t];
    red[t] = mt;
    __syncthreads();
    for (int s = 128; s > 0; s >>= 1) {
        if (t < s) red[t] = fmaxf(red[t], red[t + s]);
        __syncthreads();
    }
    if (t == 0) Msh = red[0];
    __syncthreads();
    if (t < 128) w_s[t] = __expf(mt - Msh);
    __syncthreads();

    const int slot = t >> 3, rs = t & 7;              // 32 j-quads x 8 rt-lanes
    f32x4 a = {};
#pragma unroll
    for (int i = 0; i < 16; ++i) {
        const int rt = rs + i * 8;
        half4v v = *(const half4v*)(hbar16 + ((size_t)(b * 128 + rt) * Hh + hd) * Dm + js * 128 + slot * 4);
        const float wt = w_s[rt];
        a[0] += wt * (float)v[0]; a[1] += wt * (float)v[1];
        a[2] += wt * (float)v[2]; a[3] += wt * (float)v[3];
    }
    pA[slot][rs] = a;
    __syncthreads();
    if (t < 32) {
        f32x4 s = {};
#pragma unroll
        for (int r = 0; r < 8; ++r) s += pA[t][r];
        *(f32x4*)(hb + t * 4) = s;
    }
    __syncthreads();

    const int c = t & 31, jg = t >> 5;
    float acc = 0.f;
#pragma unroll
    for (int i = 0; i < 16; ++i)
        acc += hb[jg * 16 + i] * Wv[(size_t)(js * 128 + jg * 16 + i) * DKV + hd * 32 + c];
    red[t] = acc;
    __syncthreads();
    if (t < 32) {
        float s = 0.f;
#pragma unroll
        for (int g = 0; g < 8; ++g) s += red[g * 32 + t];
        opre_part[((size_t)(b * Hh + hd) * 8 + js) * 32 + t] = s;
    }
}

// ---------------------------------------------------------------------------
// kout: grid 64 (b-merged, 16 n-cols each). Weighted den finalize (same M as
// kopre, deterministic), opre finalize, then out = opre @ Wo + bo.
// ---------------------------------------------------------------------------
__global__ __launch_bounds__(256) void kout(
        const float* __restrict__ opre_part, const float* __restrict__ m_part,
        const float* __restrict__ den_part,
        const float* __restrict__ Wo, const float* __restrict__ bo,
        float* __restrict__ out)
{
    const int nt = blockIdx.x;
    const int t = threadIdx.x;
    __shared__ float op[2][DKV];
    __shared__ float dred[32][8];
    __shared__ float Ms[32];
    __shared__ float den_s[2][16];
    __shared__ float red0[256], red1[256];

    const int pr = t >> 3, rg = t & 7;                // 32 (b,h) pairs x 8 groups
    const int pb = pr >> 4, ph = pr & 15;
    {   // max over 128 tiles
        float m = -1e30f;
#pragma unroll
        for (int i = 0; i < 16; ++i)
            m = fmaxf(m, m_part[((size_t)pb * Hh + ph) * 128 + rg + i * 8]);
        dred[pr][rg] = m;
    }
    __syncthreads();
    if (t < 32) {
        float m = -1e30f;
#pragma unroll
        for (int g = 0; g < 8; ++g) m = fmaxf(m, dred[t][g]);
        Ms[t] = m;
    }
    __syncthreads();
    {   // weighted den
        const float M = Ms[pr];
        float s = 0.f;
#pragma unroll
        for (int i = 0; i < 16; ++i) {
            const int rt = rg + i * 8;
            s += __expf(m_part[((size_t)pb * Hh + ph) * 128 + rt] - M)
               * den_part[((size_t)pb * Hh + ph) * 128 + rt];
        }
        dred[pr][rg] = s;
    }
    __syncthreads();
    if (t < 32) {
        float s = 0.f;
#pragma unroll
        for (int g = 0; g < 8; ++g) s += dred[t][g];
        den_s[t >> 4][t & 15] = s;
    }
    __syncthreads();
#pragma unroll
    for (int cc = 0; cc < 4; ++cc) {
        const int idx = cc * 256 + t;                 // 1024 = 2b x 512c
        const int b = idx >> 9, c = idx & 511;
        float s = 0.f;
#pragma unroll
        for (int js = 0; js < 8; ++js)
            s += opre_part[((size_t)(b * Hh + (c >> 5)) * 8 + js) * 32 + (c & 31)];
        op[b][c] = s / den_s[b][c >> 5];
    }
    __syncthreads();

    const int nl = t & 15, cg = t >> 4;               // 16 c-groups of 32
    const int n = nt * 16 + nl;
    float a0 = 0.f, a1 = 0.f;
#pragma unroll 8
    for (int c = cg * 32; c < cg * 32 + 32; ++c) {
        const float wv = Wo[(size_t)c * Dm + n];
        a0 += op[0][c] * wv;
        a1 += op[1][c] * wv;
    }
    red0[t] = a0; red1[t] = a1;
    __syncthreads();
    if (t < 16) {
        float s0 = 0.f, s1 = 0.f;
#pragma unroll
        for (int g = 0; g < 16; ++g) { s0 += red0[g * 16 + t]; s1 += red1[g * 16 + t]; }
        const float bv = bo[nt * 16 + t];
        out[(size_t)0 * Dm + nt * 16 + t] = bv + s0;
        out[(size_t)1 * Dm + nt * 16 + t] = bv + s1;
    }
}

// ---------------------------------------------------------------------------
extern "C" void kernel_launch(void* const* d_in, const int* in_sizes, int n_in,
                              void* d_out, int out_size, void* d_ws, size_t ws_size,
                              hipStream_t stream) {
    const float* h      = (const float*)d_in[0];
    const float* mu     = (const float*)d_in[1];
    const float* sigma  = (const float*)d_in[2];
    const float* Wq     = (const float*)d_in[3];
    const float* Wk     = (const float*)d_in[4];
    const float* Wv     = (const float*)d_in[5];
    const float* Wo     = (const float*)d_in[6];
    const float* bo     = (const float*)d_in[7];
    const float* tau_w1 = (const float*)d_in[8];
    const float* tau_b1 = (const float*)d_in[9];
    const float* tau_w2 = (const float*)d_in[10];
    const float* tau_b2 = (const float*)d_in[11];
    const float* del_w1 = (const float*)d_in[12];
    const float* del_b1 = (const float*)d_in[13];
    const float* del_w2 = (const float*)d_in[14];
    const float* del_b2 = (const float*)d_in[15];
    float* out = (float*)d_out;

    // workspace (~8.4 MB)
    _Float16* kwh16  = (_Float16*)d_ws;                     // 32768 halfs (64 KB)
    _Float16* hbar16 = kwh16 + 32768;                       // 2*128*16*1024 = 4M halfs (8 MB)
    float* m_part    = (float*)(hbar16 + (size_t)2 * 128 * Hh * Dm);  // 4096
    float* den_part  = m_part + 4096;                       // 4096
    float* opre_part = den_part + 4096;                     // 8192

    kprep2<<<dim3(32, Bb), 256, 0, stream>>>(h, mu, sigma, Wq, Wk,
                                             tau_w1, tau_b1, tau_w2, tau_b2,
                                             del_w1, del_b1, del_w2, del_b2, kwh16);
    kmid<<<dim3(128, Bb), 256, 0, stream>>>(h, kwh16, m_part, den_part, hbar16);
    kopre<<<dim3(16, Bb, 8), 256, 0, stream>>>(hbar16, m_part, Wv, opre_part);
    kout<<<64, 256, 0, stream>>>(opre_part, m_part, den_part, Wo, bo, out);
}

// Round 15
// 51.808 us; speedup vs baseline: 1.8210x; 1.8210x over previous
//
#include <hip/hip_runtime.h>
#include <hip/hip_bf16.h>

// Problem constants
#define Dm   1024
#define Hh   16
#define HDq  64
#define DKV  512
#define HID  128
#define Bb   2
#define Ll   2048
#define Ff   32

typedef _Float16 half8 __attribute__((ext_vector_type(8)));
typedef _Float16 half4v __attribute__((ext_vector_type(4)));
typedef float f32x4 __attribute__((ext_vector_type(4)));

__device__ __forceinline__ float gelu_exact(float x) {
    return 0.5f * x * (1.0f + erff(x * 0.70710678118654752f));
}

// ---------------------------------------------------------------------------
// kpart: grid 96 (b-merged). R13-proven verbatim.
// ---------------------------------------------------------------------------
__global__ __launch_bounds__(256) void kpart(
        const float* __restrict__ h, const float* __restrict__ Wq,
        const float* __restrict__ tw1, const float* __restrict__ dw1,
        float* __restrict__ hid_part, float* __restrict__ qc_part)
{
    const int bx = blockIdx.x, t = threadIdx.x;
    __shared__ float hl0[32], hl1[32];
    __shared__ float red0[256], red1[256];
    if (bx < 64) {
        const int which = bx >> 5, js = bx & 31;
        const float* w1 = which ? dw1 : tw1;
        if (t < 32)       hl0[t]      = h[((size_t)0 * Ll + (Ll - 1)) * Dm + js * 32 + t];
        else if (t < 64)  hl1[t - 32] = h[((size_t)1 * Ll + (Ll - 1)) * Dm + js * 32 + (t - 32)];
        __syncthreads();
        const int col = t & 127, rg = t >> 7;
        float a0 = 0.f, a1 = 0.f;
#pragma unroll
        for (int p = 0; p < 16; ++p) {
            const int row = p * 2 + rg;
            const float w = w1[(size_t)(js * 32 + row + 1) * HID + col];
            a0 += hl0[row] * w;
            a1 += hl1[row] * w;
        }
        red0[t] = a0; red1[t] = a1;
        __syncthreads();
        if (t < 128) {
            hid_part[((size_t)(0 * 2 + which) * 32 + js) * HID + t] = red0[t] + red0[t + 128];
            hid_part[((size_t)(1 * 2 + which) * 32 + js) * HID + t] = red1[t] + red1[t + 128];
        }
    } else {
        const int js = bx - 64;
        if (t < 32)       hl0[t]      = h[((size_t)0 * Ll + (Ll - 1)) * Dm + js * 32 + t];
        else if (t < 64)  hl1[t - 32] = h[((size_t)1 * Ll + (Ll - 1)) * Dm + js * 32 + (t - 32)];
        __syncthreads();
        float4 a0 = {0.f, 0.f, 0.f, 0.f}, a1 = {0.f, 0.f, 0.f, 0.f};
        const float* Wq0 = Wq + (size_t)(js * 32) * Dm + t * 4;
#pragma unroll
        for (int j = 0; j < 32; ++j) {
            float4 wq = *(const float4*)(Wq0 + (size_t)j * Dm);
            const float x0 = hl0[j], x1 = hl1[j];
            a0.x += x0 * wq.x; a0.y += x0 * wq.y; a0.z += x0 * wq.z; a0.w += x0 * wq.w;
            a1.x += x1 * wq.x; a1.y += x1 * wq.y; a1.z += x1 * wq.z; a1.w += x1 * wq.w;
        }
        const int col = t * 4;
        if ((col & 63) < 32) {
            const int c = (col >> 6) * 32 + (col & 31);
            *(float4*)(qc_part + ((size_t)0 * 32 + js) * DKV + c) = a0;
            *(float4*)(qc_part + ((size_t)1 * 32 + js) * DKV + c) = a1;
        }
    }
}

// ---------------------------------------------------------------------------
// kkw2: grid (32 jt, Bb). R13-proven verbatim.
// ---------------------------------------------------------------------------
__global__ __launch_bounds__(256) void kkw2(
        const float* __restrict__ mu, const float* __restrict__ sigma,
        const float* __restrict__ tw1, const float* __restrict__ tb1,
        const float* __restrict__ tw2, const float* __restrict__ tb2,
        const float* __restrict__ dw1, const float* __restrict__ db1,
        const float* __restrict__ dw2, const float* __restrict__ db2,
        const float* __restrict__ Wk,
        const float* __restrict__ hid_part, const float* __restrict__ qc_part,
        _Float16* __restrict__ kwh16)
{
    const int jt = blockIdx.x, b = blockIdx.y;
    const int t = threadIdx.x;
    __shared__ float gh[HID];
    __shared__ float red[256];
    __shared__ float wc[DKV];
    __shared__ float kl[16][36];
    __shared__ float s_tau, s_sm, s_mm;

    if (t == 0) {
        float s = 0.f;
        for (int f = 0; f < Ff; ++f) s += sigma[((size_t)b * Ll + (Ll - 1)) * Ff + f];
        s_sm = fmaxf(s / (float)Ff, 1e-6f);
    }
    if (t == 64) {
        float s = 0.f;
        for (int f = 0; f < Ff; ++f) s += mu[((size_t)b * Ll + (Ll - 1)) * Ff + f];
        s_mm = s / (float)Ff;
    }
    __syncthreads();

    if (t < 128) {
        float a = tb1[t] + s_sm * tw1[t];
#pragma unroll
        for (int s = 0; s < 32; ++s)
            a += hid_part[((size_t)(b * 2 + 0) * 32 + s) * HID + t];
        red[t] = gelu_exact(a) * tw2[t];
    } else {
        const int hh = t - 128;
        float a = db1[hh] + s_mm * dw1[hh];
#pragma unroll
        for (int s = 0; s < 32; ++s)
            a += hid_part[((size_t)(b * 2 + 1) * 32 + s) * HID + hh];
        gh[hh] = gelu_exact(a);
        red[t] = 0.f;
    }
    __syncthreads();
    for (int s = 128; s > 0; s >>= 1) {
        if (t < s) red[t] += red[t + s];
        __syncthreads();
    }
    if (t == 0) {
        float s = red[0] + tb2[0];
        s_tau = expf(fminf(fmaxf(s, -3.f), 3.f));
    }
    __syncthreads();

    const int c0 = t, c1 = t + 256;
    float d0 = db2[c0], d1 = db2[c1];
#pragma unroll 16
    for (int i = 0; i < HID; ++i) {
        const float x = gh[i];
        d0 += x * dw2[(size_t)i * DKV + c0];
        d1 += x * dw2[(size_t)i * DKV + c1];
    }
    d0 = fminf(fmaxf(d0, -5.f), 5.f);
    d1 = fminf(fmaxf(d1, -5.f), 5.f);
    float q0 = 0.f, q1 = 0.f;
#pragma unroll
    for (int s = 0; s < 32; ++s) {
        const float* qp = qc_part + ((size_t)b * 32 + s) * DKV;
        q0 += qp[c0];
        q1 += qp[c1];
    }
    const float inv_sqrt = 0.17677669529663687f;
    wc[c0] = s_tau * q0 * inv_sqrt + d0;
    wc[c1] = s_tau * q1 * inv_sqrt + d1;
    __syncthreads();

    const float w0 = wc[t * 2], w1v = wc[t * 2 + 1];
    const int hd = t >> 4;
#pragma unroll 4
    for (int jj = 0; jj < 32; ++jj) {
        const int j = jt * 32 + jj;
        float2 kv = *(const float2*)(Wk + (size_t)j * DKV + t * 2);
        float p = kv.x * w0 + kv.y * w1v;
        p += __shfl_xor(p, 1); p += __shfl_xor(p, 2);
        p += __shfl_xor(p, 4); p += __shfl_xor(p, 8);
        if ((t & 15) == 0) kl[hd][jj] = p;
    }
    __syncthreads();
    if (t < 64) {
        const int head = t & 15, jl = (t >> 4) * 8;
        half8 v;
#pragma unroll
        for (int e = 0; e < 8; ++e) v[e] = (_Float16)kl[head][jl + e];
        *(half8*)(kwh16 + ((size_t)(b * 32 + jt)) * 512 + t * 8) = v;
    }
}

// ---------------------------------------------------------------------------
// kmid: grid (128 rt, Bb) = 256 blocks, 16-row tiles; h read ONCE.
// R14-proven verbatim (fp16 hbar + per-tile max normalization).
// ---------------------------------------------------------------------------
__global__ __launch_bounds__(256) void kmid(
        const float* __restrict__ h, const _Float16* __restrict__ kwh16,
        float* __restrict__ m_part, float* __restrict__ den_part,
        _Float16* __restrict__ hbar16)
{
    __shared__ __align__(16) _Float16 Kw[16384];      // 32 KB
    __shared__ float lred[4][16][17];
    __shared__ float p_lds[16][16];
    __shared__ float m_s[16];
    const int rt = blockIdx.x, b = blockIdx.y;
    const int t = threadIdx.x;
    const int w = t >> 6, l = t & 63;
    const int rows0 = (b * 128 + rt) * 16;

#pragma unroll
    for (int i = 0; i < 8; ++i) {
        const int idx = i * 256 + t;
        *(half8*)(Kw + idx * 8) = *(const half8*)(kwh16 + (size_t)b * 16384 + idx * 8);
    }
    __syncthreads();

    f32x4 lacc = {};
    const float* ap = h + (size_t)(rows0 + (l & 15)) * Dm + (l >> 4) * 8;
#pragma unroll
    for (int ks = 0; ks < 8; ++ks) {
        const int kt = w * 8 + ks;
        float4 x0 = *(const float4*)(ap + kt * 32);
        float4 x1 = *(const float4*)(ap + kt * 32 + 4);
        half8 af;
        af[0] = (_Float16)x0.x; af[1] = (_Float16)x0.y; af[2] = (_Float16)x0.z; af[3] = (_Float16)x0.w;
        af[4] = (_Float16)x1.x; af[5] = (_Float16)x1.y; af[6] = (_Float16)x1.z; af[7] = (_Float16)x1.w;
        half8 kf = *(const half8*)(Kw + kt * 512 + l * 8);
        lacc = __builtin_amdgcn_mfma_f32_16x16x32_f16(af, kf, lacc, 0, 0, 0);
    }
#pragma unroll
    for (int r = 0; r < 4; ++r)
        lred[w][(l >> 4) * 4 + r][l & 15] = lacc[r];
    __syncthreads();

    {
        const int row = t >> 4, head = t & 15;
        float val = lred[0][row][head] + lred[1][row][head]
                  + lred[2][row][head] + lred[3][row][head];
        val = fminf(fmaxf(val, -50.f), 50.f);
        p_lds[row][head] = val;
    }
    __syncthreads();
    if (t < 16) {
        float m = -1e30f;
#pragma unroll
        for (int r = 0; r < 16; ++r) m = fmaxf(m, p_lds[r][t]);
        m_s[t] = m;
        m_part[((size_t)b * Hh + t) * 128 + rt] = m;
    }
    __syncthreads();
    {
        const int row = t >> 4, head = t & 15;
        p_lds[row][head] = __expf(p_lds[row][head] - m_s[head]);
    }
    __syncthreads();
    if (t < 16) {
        float s = 0.f;
#pragma unroll
        for (int r = 0; r < 16; ++r) s += p_lds[r][t];
        den_part[((size_t)b * Hh + t) * 128 + rt] = s;
    }

    const int j0 = (t & 63) * 16;
    const int h0 = (t >> 6) * 4;
    f32x4 acc2[4][4] = {};
#pragma unroll 4
    for (int l2 = 0; l2 < 16; ++l2) {
        const float* hr = h + (size_t)(rows0 + l2) * Dm + j0;
        f32x4 hv[4];
#pragma unroll
        for (int jj = 0; jj < 4; ++jj) hv[jj] = *(const f32x4*)(hr + jj * 4);
        f32x4 pp = *(const f32x4*)(&p_lds[l2][h0]);
#pragma unroll
        for (int hh = 0; hh < 4; ++hh)
#pragma unroll
            for (int jj = 0; jj < 4; ++jj)
                acc2[jj][hh] += hv[jj] * pp[hh];
    }
#pragma unroll
    for (int hh = 0; hh < 4; ++hh) {
        _Float16* dst = hbar16 + ((size_t)(b * 128 + rt) * Hh + h0 + hh) * Dm + j0;
        half8 v0, v1;
#pragma unroll
        for (int e = 0; e < 4; ++e) {
            v0[e]     = (_Float16)acc2[0][hh][e];
            v0[e + 4] = (_Float16)acc2[1][hh][e];
            v1[e]     = (_Float16)acc2[2][hh][e];
            v1[e + 4] = (_Float16)acc2[3][hh][e];
        }
        *(half8*)dst = v0;
        *(half8*)(dst + 8) = v1;
    }
}

// ---------------------------------------------------------------------------
// kopre: grid (16 h, Bb, 8 js). R14-proven verbatim (weighted reduce).
// ---------------------------------------------------------------------------
__global__ __launch_bounds__(256) void kopre(
        const _Float16* __restrict__ hbar16, const float* __restrict__ m_part,
        const float* __restrict__ Wv, float* __restrict__ opre_part)
{
    const int hd = blockIdx.x, b = blockIdx.y, js = blockIdx.z;
    const int t = threadIdx.x;
    __shared__ f32x4 pA[32][8];
    __shared__ float hb[128];
    __shared__ float red[256];
    __shared__ float w_s[128];
    __shared__ float Msh;

    float mt = -1e30f;
    if (t < 128) mt = m_part[((size_t)b * Hh + hd) * 128 + t];
    red[t] = mt;
    __syncthreads();
    for (int s = 128; s > 0; s >>= 1) {
        if (t < s) red[t] = fmaxf(red[t], red[t + s]);
        __syncthreads();
    }
    if (t == 0) Msh = red[0];
    __syncthreads();
    if (t < 128) w_s[t] = __expf(mt - Msh);
    __syncthreads();

    const int slot = t >> 3, rs = t & 7;
    f32x4 a = {};
#pragma unroll
    for (int i = 0; i < 16; ++i) {
        const int rt = rs + i * 8;
        half4v v = *(const half4v*)(hbar16 + ((size_t)(b * 128 + rt) * Hh + hd) * Dm + js * 128 + slot * 4);
        const float wt = w_s[rt];
        a[0] += wt * (float)v[0]; a[1] += wt * (float)v[1];
        a[2] += wt * (float)v[2]; a[3] += wt * (float)v[3];
    }
    pA[slot][rs] = a;
    __syncthreads();
    if (t < 32) {
        f32x4 s = {};
#pragma unroll
        for (int r = 0; r < 8; ++r) s += pA[t][r];
        *(f32x4*)(hb + t * 4) = s;
    }
    __syncthreads();

    const int c = t & 31, jg = t >> 5;
    float acc = 0.f;
#pragma unroll
    for (int i = 0; i < 16; ++i)
        acc += hb[jg * 16 + i] * Wv[(size_t)(js * 128 + jg * 16 + i) * DKV + hd * 32 + c];
    red[t] = acc;
    __syncthreads();
    if (t < 32) {
        float s = 0.f;
#pragma unroll
        for (int g = 0; g < 8; ++g) s += red[g * 32 + t];
        opre_part[((size_t)(b * Hh + hd) * 8 + js) * 32 + t] = s;
    }
}

// ---------------------------------------------------------------------------
// kout: grid 64 (b-merged). R14-proven verbatim (weighted den finalize).
// ---------------------------------------------------------------------------
__global__ __launch_bounds__(256) void kout(
        const float* __restrict__ opre_part, const float* __restrict__ m_part,
        const float* __restrict__ den_part,
        const float* __restrict__ Wo, const float* __restrict__ bo,
        float* __restrict__ out)
{
    const int nt = blockIdx.x;
    const int t = threadIdx.x;
    __shared__ float op[2][DKV];
    __shared__ float dred[32][8];
    __shared__ float Ms[32];
    __shared__ float den_s[2][16];
    __shared__ float red0[256], red1[256];

    const int pr = t >> 3, rg = t & 7;
    const int pb = pr >> 4, ph = pr & 15;
    {
        float m = -1e30f;
#pragma unroll
        for (int i = 0; i < 16; ++i)
            m = fmaxf(m, m_part[((size_t)pb * Hh + ph) * 128 + rg + i * 8]);
        dred[pr][rg] = m;
    }
    __syncthreads();
    if (t < 32) {
        float m = -1e30f;
#pragma unroll
        for (int g = 0; g < 8; ++g) m = fmaxf(m, dred[t][g]);
        Ms[t] = m;
    }
    __syncthreads();
    {
        const float M = Ms[pr];
        float s = 0.f;
#pragma unroll
        for (int i = 0; i < 16; ++i) {
            const int rt = rg + i * 8;
            s += __expf(m_part[((size_t)pb * Hh + ph) * 128 + rt] - M)
               * den_part[((size_t)pb * Hh + ph) * 128 + rt];
        }
        dred[pr][rg] = s;
    }
    __syncthreads();
    if (t < 32) {
        float s = 0.f;
#pragma unroll
        for (int g = 0; g < 8; ++g) s += dred[t][g];
        den_s[t >> 4][t & 15] = s;
    }
    __syncthreads();
#pragma unroll
    for (int cc = 0; cc < 4; ++cc) {
        const int idx = cc * 256 + t;
        const int b = idx >> 9, c = idx & 511;
        float s = 0.f;
#pragma unroll
        for (int js = 0; js < 8; ++js)
            s += opre_part[((size_t)(b * Hh + (c >> 5)) * 8 + js) * 32 + (c & 31)];
        op[b][c] = s / den_s[b][c >> 5];
    }
    __syncthreads();

    const int nl = t & 15, cg = t >> 4;
    const int n = nt * 16 + nl;
    float a0 = 0.f, a1 = 0.f;
#pragma unroll 8
    for (int c = cg * 32; c < cg * 32 + 32; ++c) {
        const float wv = Wo[(size_t)c * Dm + n];
        a0 += op[0][c] * wv;
        a1 += op[1][c] * wv;
    }
    red0[t] = a0; red1[t] = a1;
    __syncthreads();
    if (t < 16) {
        float s0 = 0.f, s1 = 0.f;
#pragma unroll
        for (int g = 0; g < 16; ++g) { s0 += red0[g * 16 + t]; s1 += red1[g * 16 + t]; }
        const float bv = bo[nt * 16 + t];
        out[(size_t)0 * Dm + nt * 16 + t] = bv + s0;
        out[(size_t)1 * Dm + nt * 16 + t] = bv + s1;
    }
}

// ---------------------------------------------------------------------------
extern "C" void kernel_launch(void* const* d_in, const int* in_sizes, int n_in,
                              void* d_out, int out_size, void* d_ws, size_t ws_size,
                              hipStream_t stream) {
    const float* h      = (const float*)d_in[0];
    const float* mu     = (const float*)d_in[1];
    const float* sigma  = (const float*)d_in[2];
    const float* Wq     = (const float*)d_in[3];
    const float* Wk     = (const float*)d_in[4];
    const float* Wv     = (const float*)d_in[5];
    const float* Wo     = (const float*)d_in[6];
    const float* bo     = (const float*)d_in[7];
    const float* tau_w1 = (const float*)d_in[8];
    const float* tau_b1 = (const float*)d_in[9];
    const float* tau_w2 = (const float*)d_in[10];
    const float* tau_b2 = (const float*)d_in[11];
    const float* del_w1 = (const float*)d_in[12];
    const float* del_b1 = (const float*)d_in[13];
    const float* del_w2 = (const float*)d_in[14];
    const float* del_b2 = (const float*)d_in[15];
    float* out = (float*)d_out;

    // workspace (~8.5 MB)
    _Float16* kwh16  = (_Float16*)d_ws;                     // 32768 halfs (64 KB)
    _Float16* hbar16 = kwh16 + 32768;                       // 2*128*16*1024 halfs (8 MB)
    float* m_part    = (float*)(hbar16 + (size_t)2 * 128 * Hh * Dm);  // 4096
    float* den_part  = m_part + 4096;                       // 4096
    float* opre_part = den_part + 4096;                     // 8192
    float* hid_part  = opre_part + 8192;                    // 16384
    float* qc_part   = hid_part + 16384;                    // 32768

    kpart<<<96, 256, 0, stream>>>(h, Wq, tau_w1, del_w1, hid_part, qc_part);
    kkw2<<<dim3(32, Bb), 256, 0, stream>>>(mu, sigma, tau_w1, tau_b1, tau_w2, tau_b2,
                                           del_w1, del_b1, del_w2, del_b2, Wk,
                                           hid_part, qc_part, kwh16);
    kmid<<<dim3(128, Bb), 256, 0, stream>>>(h, kwh16, m_part, den_part, hbar16);
    kopre<<<dim3(16, Bb, 8), 256, 0, stream>>>(hbar16, m_part, Wv, opre_part);
    kout<<<64, 256, 0, stream>>>(opre_part, m_part, den_part, Wo, bo, out);
}

// Round 16
// 51.122 us; speedup vs baseline: 1.8455x; 1.0134x over previous
//
#include <hip/hip_runtime.h>
#include <hip/hip_bf16.h>

// Problem constants
#define Dm   1024
#define Hh   16
#define HDq  64
#define DKV  512
#define HID  128
#define Bb   2
#define Ll   2048
#define Ff   32

typedef _Float16 half8 __attribute__((ext_vector_type(8)));
typedef _Float16 half4v __attribute__((ext_vector_type(4)));
typedef float f32x4 __attribute__((ext_vector_type(4)));

__device__ __forceinline__ float gelu_exact(float x) {
    return 0.5f * x * (1.0f + erff(x * 0.70710678118654752f));
}

// ---------------------------------------------------------------------------
// kpart: grid 96 (b-merged). R15-proven verbatim.
// ---------------------------------------------------------------------------
__global__ __launch_bounds__(256) void kpart(
        const float* __restrict__ h, const float* __restrict__ Wq,
        const float* __restrict__ tw1, const float* __restrict__ dw1,
        float* __restrict__ hid_part, float* __restrict__ qc_part)
{
    const int bx = blockIdx.x, t = threadIdx.x;
    __shared__ float hl0[32], hl1[32];
    __shared__ float red0[256], red1[256];
    if (bx < 64) {
        const int which = bx >> 5, js = bx & 31;
        const float* w1 = which ? dw1 : tw1;
        if (t < 32)       hl0[t]      = h[((size_t)0 * Ll + (Ll - 1)) * Dm + js * 32 + t];
        else if (t < 64)  hl1[t - 32] = h[((size_t)1 * Ll + (Ll - 1)) * Dm + js * 32 + (t - 32)];
        __syncthreads();
        const int col = t & 127, rg = t >> 7;
        float a0 = 0.f, a1 = 0.f;
#pragma unroll
        for (int p = 0; p < 16; ++p) {
            const int row = p * 2 + rg;
            const float w = w1[(size_t)(js * 32 + row + 1) * HID + col];
            a0 += hl0[row] * w;
            a1 += hl1[row] * w;
        }
        red0[t] = a0; red1[t] = a1;
        __syncthreads();
        if (t < 128) {
            hid_part[((size_t)(0 * 2 + which) * 32 + js) * HID + t] = red0[t] + red0[t + 128];
            hid_part[((size_t)(1 * 2 + which) * 32 + js) * HID + t] = red1[t] + red1[t + 128];
        }
    } else {
        const int js = bx - 64;
        if (t < 32)       hl0[t]      = h[((size_t)0 * Ll + (Ll - 1)) * Dm + js * 32 + t];
        else if (t < 64)  hl1[t - 32] = h[((size_t)1 * Ll + (Ll - 1)) * Dm + js * 32 + (t - 32)];
        __syncthreads();
        float4 a0 = {0.f, 0.f, 0.f, 0.f}, a1 = {0.f, 0.f, 0.f, 0.f};
        const float* Wq0 = Wq + (size_t)(js * 32) * Dm + t * 4;
#pragma unroll
        for (int j = 0; j < 32; ++j) {
            float4 wq = *(const float4*)(Wq0 + (size_t)j * Dm);
            const float x0 = hl0[j], x1 = hl1[j];
            a0.x += x0 * wq.x; a0.y += x0 * wq.y; a0.z += x0 * wq.z; a0.w += x0 * wq.w;
            a1.x += x1 * wq.x; a1.y += x1 * wq.y; a1.z += x1 * wq.z; a1.w += x1 * wq.w;
        }
        const int col = t * 4;
        if ((col & 63) < 32) {
            const int c = (col >> 6) * 32 + (col & 31);
            *(float4*)(qc_part + ((size_t)0 * 32 + js) * DKV + c) = a0;
            *(float4*)(qc_part + ((size_t)1 * 32 + js) * DKV + c) = a1;
        }
    }
}

// ---------------------------------------------------------------------------
// kkw2: grid (32 jt, Bb). R15-proven verbatim.
// ---------------------------------------------------------------------------
__global__ __launch_bounds__(256) void kkw2(
        const float* __restrict__ mu, const float* __restrict__ sigma,
        const float* __restrict__ tw1, const float* __restrict__ tb1,
        const float* __restrict__ tw2, const float* __restrict__ tb2,
        const float* __restrict__ dw1, const float* __restrict__ db1,
        const float* __restrict__ dw2, const float* __restrict__ db2,
        const float* __restrict__ Wk,
        const float* __restrict__ hid_part, const float* __restrict__ qc_part,
        _Float16* __restrict__ kwh16)
{
    const int jt = blockIdx.x, b = blockIdx.y;
    const int t = threadIdx.x;
    __shared__ float gh[HID];
    __shared__ float red[256];
    __shared__ float wc[DKV];
    __shared__ float kl[16][36];
    __shared__ float s_tau, s_sm, s_mm;

    if (t == 0) {
        float s = 0.f;
        for (int f = 0; f < Ff; ++f) s += sigma[((size_t)b * Ll + (Ll - 1)) * Ff + f];
        s_sm = fmaxf(s / (float)Ff, 1e-6f);
    }
    if (t == 64) {
        float s = 0.f;
        for (int f = 0; f < Ff; ++f) s += mu[((size_t)b * Ll + (Ll - 1)) * Ff + f];
        s_mm = s / (float)Ff;
    }
    __syncthreads();

    if (t < 128) {
        float a = tb1[t] + s_sm * tw1[t];
#pragma unroll
        for (int s = 0; s < 32; ++s)
            a += hid_part[((size_t)(b * 2 + 0) * 32 + s) * HID + t];
        red[t] = gelu_exact(a) * tw2[t];
    } else {
        const int hh = t - 128;
        float a = db1[hh] + s_mm * dw1[hh];
#pragma unroll
        for (int s = 0; s < 32; ++s)
            a += hid_part[((size_t)(b * 2 + 1) * 32 + s) * HID + hh];
        gh[hh] = gelu_exact(a);
        red[t] = 0.f;
    }
    __syncthreads();
    for (int s = 128; s > 0; s >>= 1) {
        if (t < s) red[t] += red[t + s];
        __syncthreads();
    }
    if (t == 0) {
        float s = red[0] + tb2[0];
        s_tau = expf(fminf(fmaxf(s, -3.f), 3.f));
    }
    __syncthreads();

    const int c0 = t, c1 = t + 256;
    float d0 = db2[c0], d1 = db2[c1];
#pragma unroll 16
    for (int i = 0; i < HID; ++i) {
        const float x = gh[i];
        d0 += x * dw2[(size_t)i * DKV + c0];
        d1 += x * dw2[(size_t)i * DKV + c1];
    }
    d0 = fminf(fmaxf(d0, -5.f), 5.f);
    d1 = fminf(fmaxf(d1, -5.f), 5.f);
    float q0 = 0.f, q1 = 0.f;
#pragma unroll
    for (int s = 0; s < 32; ++s) {
        const float* qp = qc_part + ((size_t)b * 32 + s) * DKV;
        q0 += qp[c0];
        q1 += qp[c1];
    }
    const float inv_sqrt = 0.17677669529663687f;
    wc[c0] = s_tau * q0 * inv_sqrt + d0;
    wc[c1] = s_tau * q1 * inv_sqrt + d1;
    __syncthreads();

    const float w0 = wc[t * 2], w1v = wc[t * 2 + 1];
    const int hd = t >> 4;
#pragma unroll 4
    for (int jj = 0; jj < 32; ++jj) {
        const int j = jt * 32 + jj;
        float2 kv = *(const float2*)(Wk + (size_t)j * DKV + t * 2);
        float p = kv.x * w0 + kv.y * w1v;
        p += __shfl_xor(p, 1); p += __shfl_xor(p, 2);
        p += __shfl_xor(p, 4); p += __shfl_xor(p, 8);
        if ((t & 15) == 0) kl[hd][jj] = p;
    }
    __syncthreads();
    if (t < 64) {
        const int head = t & 15, jl = (t >> 4) * 8;
        half8 v;
#pragma unroll
        for (int e = 0; e < 8; ++e) v[e] = (_Float16)kl[head][jl + e];
        *(half8*)(kwh16 + ((size_t)(b * 32 + jt)) * 512 + t * 8) = v;
    }
}

// ---------------------------------------------------------------------------
// kmid: grid (128 rt, Bb) = 256 blocks, NOW 512 threads (8 waves = 2/SIMD).
// 16-row tiles, h read ONCE, fp16 hbar + per-tile max norm (R14/R15 numerics).
//  phase 1: 8-wave k-split (4 k-steps each) MFMA -> max -> exp -> den
//  phase 2: 128 j-groups x 4 h-groups; 8 j x 4 h per thread.
// ---------------------------------------------------------------------------
__global__ __launch_bounds__(512) void kmid(
        const float* __restrict__ h, const _Float16* __restrict__ kwh16,
        float* __restrict__ m_part, float* __restrict__ den_part,
        _Float16* __restrict__ hbar16)
{
    __shared__ __align__(16) _Float16 Kw[16384];      // 32 KB
    __shared__ float lred[8][16][17];                 // 8.7 KB
    __shared__ float p_lds[16][16];
    __shared__ float m_s[16];
    const int rt = blockIdx.x, b = blockIdx.y;
    const int t = threadIdx.x;
    const int w = t >> 6, l = t & 63;
    const int rows0 = (b * 128 + rt) * 16;

#pragma unroll
    for (int i = 0; i < 4; ++i) {
        const int idx = i * 512 + t;
        *(half8*)(Kw + idx * 8) = *(const half8*)(kwh16 + (size_t)b * 16384 + idx * 8);
    }
    __syncthreads();

    // phase 1: one 16-row m-tile, 8-wave k-split (4 k-steps each)
    f32x4 lacc = {};
    const float* ap = h + (size_t)(rows0 + (l & 15)) * Dm + (l >> 4) * 8;
#pragma unroll
    for (int ks = 0; ks < 4; ++ks) {
        const int kt = w * 4 + ks;
        float4 x0 = *(const float4*)(ap + kt * 32);
        float4 x1 = *(const float4*)(ap + kt * 32 + 4);
        half8 af;
        af[0] = (_Float16)x0.x; af[1] = (_Float16)x0.y; af[2] = (_Float16)x0.z; af[3] = (_Float16)x0.w;
        af[4] = (_Float16)x1.x; af[5] = (_Float16)x1.y; af[6] = (_Float16)x1.z; af[7] = (_Float16)x1.w;
        half8 kf = *(const half8*)(Kw + kt * 512 + l * 8);
        lacc = __builtin_amdgcn_mfma_f32_16x16x32_f16(af, kf, lacc, 0, 0, 0);
    }
#pragma unroll
    for (int r = 0; r < 4; ++r)
        lred[w][(l >> 4) * 4 + r][l & 15] = lacc[r];
    __syncthreads();

    if (t < 256) {
        const int row = t >> 4, head = t & 15;        // 16 x 16
        float val = 0.f;
#pragma unroll
        for (int ww = 0; ww < 8; ++ww) val += lred[ww][row][head];
        val = fminf(fmaxf(val, -50.f), 50.f);
        p_lds[row][head] = val;
    }
    __syncthreads();
    if (t < 16) {
        float m = -1e30f;
#pragma unroll
        for (int r = 0; r < 16; ++r) m = fmaxf(m, p_lds[r][t]);
        m_s[t] = m;
        m_part[((size_t)b * Hh + t) * 128 + rt] = m;
    }
    __syncthreads();
    if (t < 256) {
        const int row = t >> 4, head = t & 15;
        p_lds[row][head] = __expf(p_lds[row][head] - m_s[head]);
    }
    __syncthreads();
    if (t < 16) {
        float s = 0.f;
#pragma unroll
        for (int r = 0; r < 16; ++r) s += p_lds[r][t];
        den_part[((size_t)b * Hh + t) * 128 + rt] = s;
    }

    // phase 2: thread covers 8 j x 4 heads; h rows L2-hot from phase 1
    const int j0 = (t & 127) * 8;
    const int h0 = (t >> 7) * 4;                      // wave-uniform
    f32x4 acc2[2][4] = {};                            // [j-quad][hh]
#pragma unroll 4
    for (int l2 = 0; l2 < 16; ++l2) {
        const float* hr = h + (size_t)(rows0 + l2) * Dm + j0;
        f32x4 hv0 = *(const f32x4*)hr;
        f32x4 hv1 = *(const f32x4*)(hr + 4);
        f32x4 pp = *(const f32x4*)(&p_lds[l2][h0]);
#pragma unroll
        for (int hh = 0; hh < 4; ++hh) {
            acc2[0][hh] += hv0 * pp[hh];
            acc2[1][hh] += hv1 * pp[hh];
        }
    }
#pragma unroll
    for (int hh = 0; hh < 4; ++hh) {
        _Float16* dst = hbar16 + ((size_t)(b * 128 + rt) * Hh + h0 + hh) * Dm + j0;
        half8 v;
#pragma unroll
        for (int e = 0; e < 4; ++e) {
            v[e]     = (_Float16)acc2[0][hh][e];
            v[e + 4] = (_Float16)acc2[1][hh][e];
        }
        *(half8*)dst = v;
    }
}

// ---------------------------------------------------------------------------
// kopre: grid (16 h, Bb, 8 js). R15-proven verbatim (weighted reduce).
// ---------------------------------------------------------------------------
__global__ __launch_bounds__(256) void kopre(
        const _Float16* __restrict__ hbar16, const float* __restrict__ m_part,
        const float* __restrict__ Wv, float* __restrict__ opre_part)
{
    const int hd = blockIdx.x, b = blockIdx.y, js = blockIdx.z;
    const int t = threadIdx.x;
    __shared__ f32x4 pA[32][8];
    __shared__ float hb[128];
    __shared__ float red[256];
    __shared__ float w_s[128];
    __shared__ float Msh;

    float mt = -1e30f;
    if (t < 128) mt = m_part[((size_t)b * Hh + hd) * 128 + t];
    red[t] = mt;
    __syncthreads();
    for (int s = 128; s > 0; s >>= 1) {
        if (t < s) red[t] = fmaxf(red[t], red[t + s]);
        __syncthreads();
    }
    if (t == 0) Msh = red[0];
    __syncthreads();
    if (t < 128) w_s[t] = __expf(mt - Msh);
    __syncthreads();

    const int slot = t >> 3, rs = t & 7;
    f32x4 a = {};
#pragma unroll
    for (int i = 0; i < 16; ++i) {
        const int rt = rs + i * 8;
        half4v v = *(const half4v*)(hbar16 + ((size_t)(b * 128 + rt) * Hh + hd) * Dm + js * 128 + slot * 4);
        const float wt = w_s[rt];
        a[0] += wt * (float)v[0]; a[1] += wt * (float)v[1];
        a[2] += wt * (float)v[2]; a[3] += wt * (float)v[3];
    }
    pA[slot][rs] = a;
    __syncthreads();
    if (t < 32) {
        f32x4 s = {};
#pragma unroll
        for (int r = 0; r < 8; ++r) s += pA[t][r];
        *(f32x4*)(hb + t * 4) = s;
    }
    __syncthreads();

    const int c = t & 31, jg = t >> 5;
    float acc = 0.f;
#pragma unroll
    for (int i = 0; i < 16; ++i)
        acc += hb[jg * 16 + i] * Wv[(size_t)(js * 128 + jg * 16 + i) * DKV + hd * 32 + c];
    red[t] = acc;
    __syncthreads();
    if (t < 32) {
        float s = 0.f;
#pragma unroll
        for (int g = 0; g < 8; ++g) s += red[g * 32 + t];
        opre_part[((size_t)(b * Hh + hd) * 8 + js) * 32 + t] = s;
    }
}

// ---------------------------------------------------------------------------
// kout: grid 64 (b-merged). R15-proven verbatim (weighted den finalize).
// ---------------------------------------------------------------------------
__global__ __launch_bounds__(256) void kout(
        const float* __restrict__ opre_part, const float* __restrict__ m_part,
        const float* __restrict__ den_part,
        const float* __restrict__ Wo, const float* __restrict__ bo,
        float* __restrict__ out)
{
    const int nt = blockIdx.x;
    const int t = threadIdx.x;
    __shared__ float op[2][DKV];
    __shared__ float dred[32][8];
    __shared__ float Ms[32];
    __shared__ float den_s[2][16];
    __shared__ float red0[256], red1[256];

    const int pr = t >> 3, rg = t & 7;
    const int pb = pr >> 4, ph = pr & 15;
    {
        float m = -1e30f;
#pragma unroll
        for (int i = 0; i < 16; ++i)
            m = fmaxf(m, m_part[((size_t)pb * Hh + ph) * 128 + rg + i * 8]);
        dred[pr][rg] = m;
    }
    __syncthreads();
    if (t < 32) {
        float m = -1e30f;
#pragma unroll
        for (int g = 0; g < 8; ++g) m = fmaxf(m, dred[t][g]);
        Ms[t] = m;
    }
    __syncthreads();
    {
        const float M = Ms[pr];
        float s = 0.f;
#pragma unroll
        for (int i = 0; i < 16; ++i) {
            const int rt = rg + i * 8;
            s += __expf(m_part[((size_t)pb * Hh + ph) * 128 + rt] - M)
               * den_part[((size_t)pb * Hh + ph) * 128 + rt];
        }
        dred[pr][rg] = s;
    }
    __syncthreads();
    if (t < 32) {
        float s = 0.f;
#pragma unroll
        for (int g = 0; g < 8; ++g) s += dred[t][g];
        den_s[t >> 4][t & 15] = s;
    }
    __syncthreads();
#pragma unroll
    for (int cc = 0; cc < 4; ++cc) {
        const int idx = cc * 256 + t;
        const int b = idx >> 9, c = idx & 511;
        float s = 0.f;
#pragma unroll
        for (int js = 0; js < 8; ++js)
            s += opre_part[((size_t)(b * Hh + (c >> 5)) * 8 + js) * 32 + (c & 31)];
        op[b][c] = s / den_s[b][c >> 5];
    }
    __syncthreads();

    const int nl = t & 15, cg = t >> 4;
    const int n = nt * 16 + nl;
    float a0 = 0.f, a1 = 0.f;
#pragma unroll 8
    for (int c = cg * 32; c < cg * 32 + 32; ++c) {
        const float wv = Wo[(size_t)c * Dm + n];
        a0 += op[0][c] * wv;
        a1 += op[1][c] * wv;
    }
    red0[t] = a0; red1[t] = a1;
    __syncthreads();
    if (t < 16) {
        float s0 = 0.f, s1 = 0.f;
#pragma unroll
        for (int g = 0; g < 16; ++g) { s0 += red0[g * 16 + t]; s1 += red1[g * 16 + t]; }
        const float bv = bo[nt * 16 + t];
        out[(size_t)0 * Dm + nt * 16 + t] = bv + s0;
        out[(size_t)1 * Dm + nt * 16 + t] = bv + s1;
    }
}

// ---------------------------------------------------------------------------
extern "C" void kernel_launch(void* const* d_in, const int* in_sizes, int n_in,
                              void* d_out, int out_size, void* d_ws, size_t ws_size,
                              hipStream_t stream) {
    const float* h      = (const float*)d_in[0];
    const float* mu     = (const float*)d_in[1];
    const float* sigma  = (const float*)d_in[2];
    const float* Wq     = (const float*)d_in[3];
    const float* Wk     = (const float*)d_in[4];
    const float* Wv     = (const float*)d_in[5];
    const float* Wo     = (const float*)d_in[6];
    const float* bo     = (const float*)d_in[7];
    const float* tau_w1 = (const float*)d_in[8];
    const float* tau_b1 = (const float*)d_in[9];
    const float* tau_w2 = (const float*)d_in[10];
    const float* tau_b2 = (const float*)d_in[11];
    const float* del_w1 = (const float*)d_in[12];
    const float* del_b1 = (const float*)d_in[13];
    const float* del_w2 = (const float*)d_in[14];
    const float* del_b2 = (const float*)d_in[15];
    float* out = (float*)d_out;

    // workspace (~8.5 MB)
    _Float16* kwh16  = (_Float16*)d_ws;                     // 32768 halfs (64 KB)
    _Float16* hbar16 = kwh16 + 32768;                       // 2*128*16*1024 halfs (8 MB)
    float* m_part    = (float*)(hbar16 + (size_t)2 * 128 * Hh * Dm);  // 4096
    float* den_part  = m_part + 4096;                       // 4096
    float* opre_part = den_part + 4096;                     // 8192
    float* hid_part  = opre_part + 8192;                    // 16384
    float* qc_part   = hid_part + 16384;                    // 32768

    kpart<<<96, 256, 0, stream>>>(h, Wq, tau_w1, del_w1, hid_part, qc_part);
    kkw2<<<dim3(32, Bb), 256, 0, stream>>>(mu, sigma, tau_w1, tau_b1, tau_w2, tau_b2,
                                           del_w1, del_b1, del_w2, del_b2, Wk,
                                           hid_part, qc_part, kwh16);
    kmid<<<dim3(128, Bb), 512, 0, stream>>>(h, kwh16, m_part, den_part, hbar16);
    kopre<<<dim3(16, Bb, 8), 256, 0, stream>>>(hbar16, m_part, Wv, opre_part);
    kout<<<64, 256, 0, stream>>>(opre_part, m_part, den_part, Wo, bo, out);
}